// Round 3
// baseline (318.039 us; speedup 1.0000x reference)
//
#include <hip/hip_runtime.h>
#include <hip/hip_bf16.h>

#define T_TOK 2048
#define HID   1024
#define EXP   64
#define TOPK  8
#define IMED  512

typedef __bf16 bf16x8 __attribute__((ext_vector_type(8)));
typedef float f32x4 __attribute__((ext_vector_type(4)));
typedef unsigned short ushortx8 __attribute__((ext_vector_type(8)));
typedef unsigned short ushortx4 __attribute__((ext_vector_type(4)));

__constant__ int kShifts[8] = {0, 16, 4, 20, 8, 24, 12, 28};

__device__ __forceinline__ void async16(const void* g, void* l) {
  __builtin_amdgcn_global_load_lds((const __attribute__((address_space(1))) void*)g,
                                   (__attribute__((address_space(3))) void*)l, 16, 0, 0);
}

// round-to-nearest-even f32 -> bf16 bits
__device__ __forceinline__ unsigned short f2bf(float f) {
  unsigned u = __builtin_bit_cast(unsigned, f);
  unsigned r = (u + 0x7fffu + ((u >> 16) & 1u)) >> 16;
  return (unsigned short)r;
}

__device__ __forceinline__ float bf2f(unsigned short b) {
  unsigned u = ((unsigned)b) << 16;
  return __builtin_bit_cast(float, u);
}

// ---------------- Routing: 256 thr/token, LDS x-row, fused bf16 cast (verified R4/R8) ----------------
__global__ __launch_bounds__(256) void routing_kernel(
    const float* __restrict__ x, const float* __restrict__ gate_w,
    int* __restrict__ counts, int* __restrict__ tok_list,
    int* __restrict__ hslot_list, float* __restrict__ cw_list,
    unsigned short* __restrict__ xbf) {
  const int t = blockIdx.x;
  const int tid = threadIdx.x;
  __shared__ float xs[HID];
  __shared__ float part[64][4];

  float4 v = reinterpret_cast<const float4*>(x + (size_t)t * HID)[tid];
  reinterpret_cast<float4*>(xs)[tid] = v;
  ushortx4 o;
  o[0] = f2bf(v.x); o[1] = f2bf(v.y); o[2] = f2bf(v.z); o[3] = f2bf(v.w);
  *reinterpret_cast<ushortx4*>(xbf + (size_t)t * HID + tid * 4) = o;
  __syncthreads();

  const int e = tid >> 2, seg = tid & 3;
  const float4* gp = reinterpret_cast<const float4*>(gate_w + (size_t)e * HID);
  const float4* xp = reinterpret_cast<const float4*>(xs);
  float acc = 0.f;
#pragma unroll 8
  for (int i = 0; i < 64; ++i) {
    float4 a = xp[i * 4 + seg];
    float4 b = gp[i * 4 + seg];
    acc = fmaf(a.x, b.x, acc);
    acc = fmaf(a.y, b.y, acc);
    acc = fmaf(a.z, b.z, acc);
    acc = fmaf(a.w, b.w, acc);
  }
  part[e][seg] = acc;
  __syncthreads();

  if (tid < 64) {
    float4 p = reinterpret_cast<const float4*>(part)[tid];
    float lg = (p.x + p.y) + (p.z + p.w);

    float m = lg;
    for (int off = 32; off; off >>= 1) m = fmaxf(m, __shfl_xor(m, off));
    float pe = expf(lg - m);
    float s = pe;
    for (int off = 32; off; off >>= 1) s += __shfl_xor(s, off);
    float prob = pe / s;

    float pcur = prob;
    float myv = 0.f;
    int myi = -1;
    float tsum = 0.f;
    for (int k = 0; k < TOPK; ++k) {
      float vv = pcur;
      int idx = tid;
      for (int off = 32; off; off >>= 1) {
        float ov = __shfl_xor(vv, off);
        int oi = __shfl_xor(idx, off);
        if (ov > vv || (ov == vv && oi < idx)) { vv = ov; idx = oi; }
      }
      tsum += vv;
      if (tid == k) { myv = vv; myi = idx; }
      if (tid == idx) pcur = -1.f;
    }

    if (tid < TOPK) {
      float cw = myv / tsum;
      int ex = myi;
      int slot = atomicAdd(&counts[ex], 1);
      tok_list[ex * T_TOK + slot] = t;
      hslot_list[ex * T_TOK + slot] = t * TOPK + tid;
      cw_list[ex * T_TOK + slot] = cw;
    }
  }
}

// ---------------- AWQ dequant -> bf16, transposed to [n][k] (verified R2/R3/R8) ----------------
__global__ __launch_bounds__(256) void dequant_kernel(
    const int* __restrict__ qw, const int* __restrict__ qz,
    const float* __restrict__ sc, unsigned short* __restrict__ outw,
    int K, int C) {
  __shared__ unsigned short tile[128][72];
  const int kk = threadIdx.x & 63;
  const int cc4 = threadIdx.x >> 6;  // 0..3
  const int k = blockIdx.y * 64 + kk;
  const int c0 = blockIdx.x * 16 + cc4 * 4;
  const int g = k >> 7;
  const int N = C * 8;

  int4 q4 = *reinterpret_cast<const int4*>(qw + (size_t)k * C + c0);
  int4 z4 = *reinterpret_cast<const int4*>(qz + (size_t)g * C + c0);
  const float* sp = sc + (size_t)g * N + (size_t)c0 * 8;
  const int qs[4] = {q4.x, q4.y, q4.z, q4.w};
  const int zs[4] = {z4.x, z4.y, z4.z, z4.w};
#pragma unroll
  for (int it = 0; it < 4; ++it) {
    const unsigned q = (unsigned)qs[it];
    const unsigned z = (unsigned)zs[it];
    float4 s0 = *reinterpret_cast<const float4*>(sp + it * 8);
    float4 s1 = *reinterpret_cast<const float4*>(sp + it * 8 + 4);
    float sv[8] = {s0.x, s0.y, s0.z, s0.w, s1.x, s1.y, s1.z, s1.w};
#pragma unroll
    for (int j = 0; j < 8; ++j) {
      const int sh = kShifts[j];
      const float val = (float)((int)((q >> sh) & 15u) - (int)((z >> sh) & 15u));
      tile[(cc4 * 4 + it) * 8 + j][kk] = f2bf(val * sv[j]);
    }
  }
  __syncthreads();
  const size_t kbase = (size_t)blockIdx.y * 64;
#pragma unroll
  for (int it = 0; it < 4; ++it) {
    const int slot = threadIdx.x + 256 * it;
    const int row = slot >> 3, seg = slot & 7;
    const int n = blockIdx.x * 128 + row;
    *reinterpret_cast<ushortx8*>(outw + (size_t)n * K + kbase + seg * 8) =
        *reinterpret_cast<const ushortx8*>(&tile[row][seg * 8]);
  }
}

// ---------------- MFMA GEMM1, M64 x N64 tile, BK=64, 3-buf ring, counted vmcnt (T4) ----------------
// h[hslot, i] = silu(x . w1^T) * cw.  Waves 2x2, wave tile 32x32, acc[2][2].
// Per K-step: waitcnt vmcnt(4) [own stage-t loads done, stage-t+1 in flight] -> s_barrier
// -> issue stage(t+2) -> ds_read+MFMA on buf t%3.  Loads never drain to 0 in the loop.
__global__ __launch_bounds__(256) void mfma_gemm1(
    const unsigned short* __restrict__ xbf, const unsigned short* __restrict__ dqw1,
    const int* __restrict__ counts, const int* __restrict__ tok_list,
    const int* __restrict__ hslot_list, const float* __restrict__ cw_list,
    unsigned short* __restrict__ h_buf) {
  const int e = blockIdx.z;
  const int n_e = counts[e];
  const int t0 = blockIdx.y * 64;
  if (t0 >= n_e) return;
  const int ntile = blockIdx.x;  // 0..7 (64 cols each)
  const int tid = threadIdx.x;
  const int wave = tid >> 6, lane = tid & 63;
  const int wm = wave & 1, wn = wave >> 1;

  __shared__ unsigned short As[3 * 2 * 64 * 32];  // 3 bufs x 8KB
  __shared__ unsigned short Bs[3 * 2 * 64 * 32];  // 3 bufs x 8KB (total 48KB)

  // staging: thread -> row tid>>2, 16B seg tid&3; kk-half at +64B global / +4KB LDS
  const int srow = tid >> 2;        // 0..63
  const int bcol = (tid & 3) * 16;  // 0/16/32/48
  const int ta = tok_list[e * T_TOK + min(t0 + srow, n_e - 1)];
  const char* ga = (const char*)(xbf + (size_t)ta * HID) + bcol;
  const int nb = e * IMED + ntile * 64 + srow;
  const char* gb = (const char*)(dqw1 + (size_t)nb * HID) + bcol;

  f32x4 acc[2][2];
#pragma unroll
  for (int i = 0; i < 2; ++i)
#pragma unroll
    for (int j = 0; j < 2; ++j) acc[i][j] = (f32x4){0.f, 0.f, 0.f, 0.f};

  const int fr = lane & 15, fq = lane >> 4;

  auto stage = [&](int b) {
    char* la = (char*)As + b * 8192 + wave * 1024;  // wave-uniform base; HW adds lane*16
    char* lb = (char*)Bs + b * 8192 + wave * 1024;
    async16(ga, la);
    async16(ga + 64, la + 4096);
    async16(gb, lb);
    async16(gb + 64, lb + 4096);
    ga += 128; gb += 128;
  };

  stage(0);
  stage(1);
  int cb = 0, sb = 2;
  for (int k0 = 0; k0 < HID; k0 += 64) {
    if (k0 + 64 < HID) {
      asm volatile("s_waitcnt vmcnt(4)" ::: "memory");
    } else {
      asm volatile("s_waitcnt vmcnt(0)" ::: "memory");
    }
    __builtin_amdgcn_s_barrier();
    asm volatile("" ::: "memory");
    if (k0 + 128 < HID) {
      stage(sb);
      sb = (sb == 2) ? 0 : sb + 1;
    }
    const unsigned short* Ab = As + cb * 4096;
    const unsigned short* Bb = Bs + cb * 4096;
#pragma unroll
    for (int kk = 0; kk < 2; ++kk) {
      bf16x8 af[2], bfr[2];
#pragma unroll
      for (int i = 0; i < 2; ++i)
        af[i] = *reinterpret_cast<const bf16x8*>(&Ab[kk * 2048 + (wm * 32 + i * 16 + fr) * 32 + fq * 8]);
#pragma unroll
      for (int j = 0; j < 2; ++j)
        bfr[j] = *reinterpret_cast<const bf16x8*>(&Bb[kk * 2048 + (wn * 32 + j * 16 + fr) * 32 + fq * 8]);
#pragma unroll
      for (int i = 0; i < 2; ++i)
#pragma unroll
        for (int j = 0; j < 2; ++j)
          acc[i][j] = __builtin_amdgcn_mfma_f32_16x16x32_bf16(af[i], bfr[j], acc[i][j], 0, 0, 0);
    }
    cb = (cb == 2) ? 0 : cb + 1;
  }

  // epilogue: C/D map col = lane&15, row = (lane>>4)*4 + reg
#pragma unroll
  for (int i = 0; i < 2; ++i) {
#pragma unroll
    for (int r = 0; r < 4; ++r) {
      const int grow = t0 + wm * 32 + i * 16 + fq * 4 + r;
      if (grow < n_e) {
        const float cw = cw_list[e * T_TOK + grow];
        const int hs = hslot_list[e * T_TOK + grow];
        unsigned short* dst = h_buf + (size_t)hs * IMED + ntile * 64 + wn * 32 + fr;
#pragma unroll
        for (int j = 0; j < 2; ++j) {
          const float v = acc[i][j][r];
          dst[j * 16] = f2bf((v / (1.f + expf(-v))) * cw);
        }
      }
    }
  }
}

// ---------------- MFMA GEMM2, M64 x N64 tile, BK=64, 3-buf ring, counted vmcnt (T4) ----------------
__global__ __launch_bounds__(256) void mfma_gemm2(
    const unsigned short* __restrict__ h_buf, const unsigned short* __restrict__ dqw2,
    const int* __restrict__ counts, const int* __restrict__ hslot_list,
    unsigned short* __restrict__ p_buf) {
  const int e = blockIdx.z;
  const int n_e = counts[e];
  const int t0 = blockIdx.y * 64;
  if (t0 >= n_e) return;
  const int ntile = blockIdx.x;  // 0..15 (64 cols each)
  const int tid = threadIdx.x;
  const int wave = tid >> 6, lane = tid & 63;
  const int wm = wave & 1, wn = wave >> 1;

  __shared__ unsigned short As[3 * 2 * 64 * 32];
  __shared__ unsigned short Bs[3 * 2 * 64 * 32];

  const int srow = tid >> 2;
  const int bcol = (tid & 3) * 16;
  const int ha = hslot_list[e * T_TOK + min(t0 + srow, n_e - 1)];
  const char* ga = (const char*)(h_buf + (size_t)ha * IMED) + bcol;
  const int nb = e * HID + ntile * 64 + srow;
  const char* gb = (const char*)(dqw2 + (size_t)nb * IMED) + bcol;

  f32x4 acc[2][2];
#pragma unroll
  for (int i = 0; i < 2; ++i)
#pragma unroll
    for (int j = 0; j < 2; ++j) acc[i][j] = (f32x4){0.f, 0.f, 0.f, 0.f};

  const int fr = lane & 15, fq = lane >> 4;

  auto stage = [&](int b) {
    char* la = (char*)As + b * 8192 + wave * 1024;
    char* lb = (char*)Bs + b * 8192 + wave * 1024;
    async16(ga, la);
    async16(ga + 64, la + 4096);
    async16(gb, lb);
    async16(gb + 64, lb + 4096);
    ga += 128; gb += 128;
  };

  stage(0);
  stage(1);
  int cb = 0, sb = 2;
  for (int k0 = 0; k0 < IMED; k0 += 64) {
    if (k0 + 64 < IMED) {
      asm volatile("s_waitcnt vmcnt(4)" ::: "memory");
    } else {
      asm volatile("s_waitcnt vmcnt(0)" ::: "memory");
    }
    __builtin_amdgcn_s_barrier();
    asm volatile("" ::: "memory");
    if (k0 + 128 < IMED) {
      stage(sb);
      sb = (sb == 2) ? 0 : sb + 1;
    }
    const unsigned short* Ab = As + cb * 4096;
    const unsigned short* Bb = Bs + cb * 4096;
#pragma unroll
    for (int kk = 0; kk < 2; ++kk) {
      bf16x8 af[2], bfr[2];
#pragma unroll
      for (int i = 0; i < 2; ++i)
        af[i] = *reinterpret_cast<const bf16x8*>(&Ab[kk * 2048 + (wm * 32 + i * 16 + fr) * 32 + fq * 8]);
#pragma unroll
      for (int j = 0; j < 2; ++j)
        bfr[j] = *reinterpret_cast<const bf16x8*>(&Bb[kk * 2048 + (wn * 32 + j * 16 + fr) * 32 + fq * 8]);
#pragma unroll
      for (int i = 0; i < 2; ++i)
#pragma unroll
        for (int j = 0; j < 2; ++j)
          acc[i][j] = __builtin_amdgcn_mfma_f32_16x16x32_bf16(af[i], bfr[j], acc[i][j], 0, 0, 0);
    }
    cb = (cb == 2) ? 0 : cb + 1;
  }

  // epilogue: plain bf16 partial stores (no atomics); every (hslot, col) written once
#pragma unroll
  for (int i = 0; i < 2; ++i) {
#pragma unroll
    for (int r = 0; r < 4; ++r) {
      const int grow = t0 + wm * 32 + i * 16 + fq * 4 + r;
      if (grow < n_e) {
        const int hs = hslot_list[e * T_TOK + grow];
        unsigned short* dst = p_buf + (size_t)hs * HID + ntile * 64 + wn * 32 + fr;
#pragma unroll
        for (int j = 0; j < 2; ++j) dst[j * 16] = f2bf(acc[i][j][r]);
      }
    }
  }
}

// ---------------- Reduce 8 partials per token -> out (fp32, verified R3/R8) ----------------
__global__ __launch_bounds__(256) void reduce_kernel(const unsigned short* __restrict__ p_buf,
                                                     float* __restrict__ out) {
  const int idx = blockIdx.x * 256 + threadIdx.x;
  const int t = idx >> 7;
  const int c0 = (idx & 127) * 8;
  float s[8] = {0.f, 0.f, 0.f, 0.f, 0.f, 0.f, 0.f, 0.f};
#pragma unroll
  for (int k = 0; k < TOPK; ++k) {
    ushortx8 v = *reinterpret_cast<const ushortx8*>(p_buf + ((size_t)t * TOPK + k) * HID + c0);
#pragma unroll
    for (int j = 0; j < 8; ++j) s[j] += bf2f(v[j]);
  }
  float* dst = out + (size_t)t * HID + c0;
  *reinterpret_cast<float4*>(dst) = make_float4(s[0], s[1], s[2], s[3]);
  *reinterpret_cast<float4*>(dst + 4) = make_float4(s[4], s[5], s[6], s[7]);
}

extern "C" void kernel_launch(void* const* d_in, const int* in_sizes, int n_in,
                              void* d_out, int out_size, void* d_ws, size_t ws_size,
                              hipStream_t stream) {
  const float* x      = (const float*)d_in[0];
  const float* gate_w = (const float*)d_in[1];
  const int*   qw1    = (const int*)d_in[2];
  const int*   qz1    = (const int*)d_in[3];
  const float* sc1    = (const float*)d_in[4];
  const int*   qw2    = (const int*)d_in[5];
  const int*   qz2    = (const int*)d_in[6];
  const float* sc2    = (const float*)d_in[7];
  float* out = (float*)d_out;

  // workspace layout (R3/R8-verified; p_buf aliases dqw1, dead after gemm1)
  char* ws = (char*)d_ws;
  int* counts           = (int*)(ws);                        // 256 B
  int* tok_list         = (int*)(ws + 256);                  // 512 KB
  int* hslot_list       = (int*)(ws + 524544);               // 512 KB
  float* cw_list        = (float*)(ws + 1048832);            // 512 KB
  unsigned short* h_buf = (unsigned short*)(ws + 1573120);   // 16.8 MB
  unsigned short* xbf   = (unsigned short*)(ws + 18350336);  // 4.2 MB
  unsigned short* dqw1  = (unsigned short*)(ws + 22544640);  // 67 MB
  unsigned short* dqw2  = (unsigned short*)(ws + 89653504);  // 67 MB
  unsigned short* p_buf = (unsigned short*)(ws + 22544640);  // 33.6 MB (aliases dqw1)

  hipMemsetAsync(counts, 0, 256, stream);

  routing_kernel<<<T_TOK, 256, 0, stream>>>(x, gate_w, counts, tok_list, hslot_list, cw_list, xbf);
  dequant_kernel<<<dim3(4096 / 16, 1024 / 64), 256, 0, stream>>>(qw1, qz1, sc1, dqw1, HID, 4096);
  dequant_kernel<<<dim3(8192 / 16, 512 / 64), 256, 0, stream>>>(qw2, qz2, sc2, dqw2, IMED, 8192);

  mfma_gemm1<<<dim3(IMED / 64, T_TOK / 64, EXP), 256, 0, stream>>>(
      xbf, dqw1, counts, tok_list, hslot_list, cw_list, h_buf);
  mfma_gemm2<<<dim3(HID / 64, T_TOK / 64, EXP), 256, 0, stream>>>(
      h_buf, dqw2, counts, hslot_list, p_buf);
  reduce_kernel<<<(T_TOK * HID / 8) / 256, 256, 0, stream>>>(p_buf, out);
}

// Round 4
// 292.170 us; speedup vs baseline: 1.0885x; 1.0885x over previous
//
#include <hip/hip_runtime.h>
#include <hip/hip_bf16.h>

#define T_TOK 2048
#define HID   1024
#define EXP   64
#define TOPK  8
#define IMED  512
#define N1 (EXP * IMED)   // 32768
#define C1 (N1 / 8)       // 4096
#define N2 (EXP * HID)    // 65536
#define C2 (N2 / 8)       // 8192

typedef __bf16 bf16x8 __attribute__((ext_vector_type(8)));
typedef float f32x4 __attribute__((ext_vector_type(4)));
typedef unsigned short ushortx8 __attribute__((ext_vector_type(8)));
typedef unsigned short ushortx4 __attribute__((ext_vector_type(4)));

__constant__ int kShifts[8] = {0, 16, 4, 20, 8, 24, 12, 28};

__device__ __forceinline__ void async16(const void* g, void* l) {
  __builtin_amdgcn_global_load_lds((const __attribute__((address_space(1))) void*)g,
                                   (__attribute__((address_space(3))) void*)l, 16, 0, 0);
}

// round-to-nearest-even f32 -> bf16 bits
__device__ __forceinline__ unsigned short f2bf(float f) {
  unsigned u = __builtin_bit_cast(unsigned, f);
  unsigned r = (u + 0x7fffu + ((u >> 16) & 1u)) >> 16;
  return (unsigned short)r;
}

__device__ __forceinline__ float bf2f(unsigned short b) {
  unsigned u = ((unsigned)b) << 16;
  return __builtin_bit_cast(float, u);
}

// dequant 8 nibbles (along k) of one dword: (q - z) * s with w = -z*s prefolded
__device__ __forceinline__ bf16x8 unpack8(unsigned q, float s, float w) {
  bf16x8 r;
#pragma unroll
  for (int i = 0; i < 8; ++i) {
    const float qf = (float)((q >> (4 * i)) & 15u);
    r[i] = (__bf16)fmaf(qf, s, w);
  }
  return r;
}

// ---------------- Routing: 256 thr/token, LDS x-row, fused bf16 cast (verified R4/R8) ----------------
__global__ __launch_bounds__(256) void routing_kernel(
    const float* __restrict__ x, const float* __restrict__ gate_w,
    int* __restrict__ counts, int* __restrict__ tok_list,
    int* __restrict__ hslot_list, float* __restrict__ cw_list,
    unsigned short* __restrict__ xbf) {
  const int t = blockIdx.x;
  const int tid = threadIdx.x;
  __shared__ float xs[HID];
  __shared__ float part[64][4];

  float4 v = reinterpret_cast<const float4*>(x + (size_t)t * HID)[tid];
  reinterpret_cast<float4*>(xs)[tid] = v;
  ushortx4 o;
  o[0] = f2bf(v.x); o[1] = f2bf(v.y); o[2] = f2bf(v.z); o[3] = f2bf(v.w);
  *reinterpret_cast<ushortx4*>(xbf + (size_t)t * HID + tid * 4) = o;
  __syncthreads();

  const int e = tid >> 2, seg = tid & 3;
  const float4* gp = reinterpret_cast<const float4*>(gate_w + (size_t)e * HID);
  const float4* xp = reinterpret_cast<const float4*>(xs);
  float acc = 0.f;
#pragma unroll 8
  for (int i = 0; i < 64; ++i) {
    float4 a = xp[i * 4 + seg];
    float4 b = gp[i * 4 + seg];
    acc = fmaf(a.x, b.x, acc);
    acc = fmaf(a.y, b.y, acc);
    acc = fmaf(a.z, b.z, acc);
    acc = fmaf(a.w, b.w, acc);
  }
  part[e][seg] = acc;
  __syncthreads();

  if (tid < 64) {
    float4 p = reinterpret_cast<const float4*>(part)[tid];
    float lg = (p.x + p.y) + (p.z + p.w);

    float m = lg;
    for (int off = 32; off; off >>= 1) m = fmaxf(m, __shfl_xor(m, off));
    float pe = expf(lg - m);
    float s = pe;
    for (int off = 32; off; off >>= 1) s += __shfl_xor(s, off);
    float prob = pe / s;

    float pcur = prob;
    float myv = 0.f;
    int myi = -1;
    float tsum = 0.f;
    for (int k = 0; k < TOPK; ++k) {
      float vv = pcur;
      int idx = tid;
      for (int off = 32; off; off >>= 1) {
        float ov = __shfl_xor(vv, off);
        int oi = __shfl_xor(idx, off);
        if (ov > vv || (ov == vv && oi < idx)) { vv = ov; idx = oi; }
      }
      tsum += vv;
      if (tid == k) { myv = vv; myi = idx; }
      if (tid == idx) pcur = -1.f;
    }

    if (tid < TOPK) {
      float cw = myv / tsum;
      int ex = myi;
      int slot = atomicAdd(&counts[ex], 1);
      tok_list[ex * T_TOK + slot] = t;
      hslot_list[ex * T_TOK + slot] = t * TOPK + tid;
      cw_list[ex * T_TOK + slot] = cw;
    }
  }
}

// ---------------- Repack AWQ nibbles: [K][N/8] along-N (perm) -> qk[n/16][K/8][16] along-K ----------------
// grid: (C/512, K/8); thread owns 2 consecutive qw columns (16 consecutive n), writes 64B.
__global__ __launch_bounds__(256) void repack_kernel(
    const int* __restrict__ qw, unsigned* __restrict__ qk, int K, int C) {
  const int kd = blockIdx.y;        // k-octet index
  const int c = blockIdx.x * 512 + threadIdx.x * 2;
  unsigned q[8][2];
#pragma unroll
  for (int r = 0; r < 8; ++r) {
    const int2 v = *reinterpret_cast<const int2*>(qw + (size_t)(kd * 8 + r) * C + c);
    q[r][0] = (unsigned)v.x;
    q[r][1] = (unsigned)v.y;
  }
  unsigned outd[16];
#pragma unroll
  for (int ci = 0; ci < 2; ++ci) {
#pragma unroll
    for (int jj = 0; jj < 8; ++jj) {
      const int sh = kShifts[jj];
      unsigned o = 0;
#pragma unroll
      for (int r = 0; r < 8; ++r) o |= ((q[r][ci] >> sh) & 0xFu) << (4 * r);
      outd[ci * 8 + jj] = o;  // n = c*8 + ci*8 + jj (n&15 = ci*8+jj)
    }
  }
  unsigned* dst = qk + ((size_t)(c >> 1) * (K / 8) + kd) * 16;
#pragma unroll
  for (int i = 0; i < 4; ++i)
    *reinterpret_cast<uint4*>(dst + i * 4) = *reinterpret_cast<const uint4*>(&outd[i * 4]);
}

// ---------------- MFMA GEMM1, M64 x N64, BK=64 dbuf A-in-LDS (swizzled), B reg-dequant from qk1 ----------------
__global__ __launch_bounds__(256) void mfma_gemm1(
    const unsigned short* __restrict__ xbf, const unsigned* __restrict__ qk1,
    const int* __restrict__ qz1, const float* __restrict__ sc1,
    const int* __restrict__ counts, const int* __restrict__ tok_list,
    const int* __restrict__ hslot_list, const float* __restrict__ cw_list,
    unsigned short* __restrict__ h_buf) {
  const int e = blockIdx.z;
  const int n_e = counts[e];
  const int t0 = blockIdx.y * 64;
  if (t0 >= n_e) return;
  const int ntile = blockIdx.x;  // 0..7
  const int tid = threadIdx.x;
  const int wave = tid >> 6, lane = tid & 63;
  const int wm = wave & 1, wn = wave >> 1;
  const int fr = lane & 15, fq = lane >> 4;

  __shared__ unsigned short As[2][64 * 64];  // 2 x 8KB, rows 128B, XOR-swizzled source

  // A staging: thread t -> round r row = r*32 + (t>>3); source col pre-swizzled so that
  // linear LDS dest (r*4096 + t*16) holds global (row, colb ^ ((row&7)<<4)).
  const int arow = tid >> 3;                                   // 0..31
  const int acb = ((tid & 7) ^ ((tid >> 3) & 7)) * 16;         // pre-swizzled byte col
  const int ta0 = tok_list[e * T_TOK + min(t0 + arow, n_e - 1)];
  const int ta1 = tok_list[e * T_TOK + min(t0 + 32 + arow, n_e - 1)];
  const char* ga0 = (const char*)(xbf + (size_t)ta0 * HID) + acb;
  const char* ga1 = (const char*)(xbf + (size_t)ta1 * HID) + acb;

  auto stage = [&](int b) {
    char* l = (char*)&As[b][0] + wave * 1024;  // + HW lane*16
    async16(ga0, l);
    async16(ga1, l + 4096);
    ga0 += 128; ga1 += 128;
  };

  // B: qk1[n>>4][k/8][16] dwords; per-lane base for fragment j (n = nbase + j*16 + fr)
  const int nbase = e * IMED + ntile * 64 + wn * 32;
  const unsigned* bl0 = qk1 + (size_t)(nbase >> 4) * 2048 + fq * 16 + fr;  // (HID/8)*16 = 2048
  const unsigned* bl1 = bl0 + 2048;
  const int shz = ((fr >> 1) & 3) * 4 + (fr & 1) * 16;  // = kShifts[fr&7]

  f32x4 acc[2][2];
#pragma unroll
  for (int i = 0; i < 2; ++i)
#pragma unroll
    for (int j = 0; j < 2; ++j) acc[i][j] = (f32x4){0.f, 0.f, 0.f, 0.f};

  stage(0);
  unsigned cb00 = bl0[0], cb01 = bl0[64], cb10 = bl1[0], cb11 = bl1[64];
  int p = 0;
#pragma unroll 1
  for (int g = 0; g < HID / 128; ++g) {
    const float s0f = sc1[(size_t)g * N1 + nbase + fr];
    const float s1f = sc1[(size_t)g * N1 + nbase + 16 + fr];
    const unsigned zd0 = (unsigned)qz1[(size_t)g * C1 + (nbase >> 3) + (fr >> 3)];
    const unsigned zd1 = (unsigned)qz1[(size_t)g * C1 + 2 + (nbase >> 3) + (fr >> 3)];
    const float w0f = -(float)((zd0 >> shz) & 15u) * s0f;
    const float w1f = -(float)((zd1 >> shz) & 15u) * s1f;
#pragma unroll
    for (int hh = 0; hh < 2; ++hh) {
      const int k0 = g * 128 + hh * 64;
      __syncthreads();  // As[p] ready (drains stage + B prefetch)
      if (k0 + 64 < HID) stage(p ^ 1);
      unsigned nb00 = 0, nb01 = 0, nb10 = 0, nb11 = 0;
      if (k0 + 64 < HID) {
        const unsigned* q0 = bl0 + (k0 + 64) * 2;
        const unsigned* q1 = bl1 + (k0 + 64) * 2;
        nb00 = q0[0]; nb01 = q0[64]; nb10 = q1[0]; nb11 = q1[64];
      }
      const bf16x8 b00 = unpack8(cb00, s0f, w0f);
      const bf16x8 b01 = unpack8(cb01, s0f, w0f);
      const bf16x8 b10 = unpack8(cb10, s1f, w1f);
      const bf16x8 b11 = unpack8(cb11, s1f, w1f);
#pragma unroll
      for (int kk = 0; kk < 2; ++kk) {
        bf16x8 af[2];
#pragma unroll
        for (int i = 0; i < 2; ++i) {
          const int row = wm * 32 + i * 16 + fr;
          af[i] = *reinterpret_cast<const bf16x8*>(
              &As[p][row * 64 + (((kk * 4 + fq) ^ (fr & 7)) * 8)]);
        }
        const bf16x8 b0 = kk ? b01 : b00;
        const bf16x8 b1 = kk ? b11 : b10;
        acc[0][0] = __builtin_amdgcn_mfma_f32_16x16x32_bf16(af[0], b0, acc[0][0], 0, 0, 0);
        acc[0][1] = __builtin_amdgcn_mfma_f32_16x16x32_bf16(af[0], b1, acc[0][1], 0, 0, 0);
        acc[1][0] = __builtin_amdgcn_mfma_f32_16x16x32_bf16(af[1], b0, acc[1][0], 0, 0, 0);
        acc[1][1] = __builtin_amdgcn_mfma_f32_16x16x32_bf16(af[1], b1, acc[1][1], 0, 0, 0);
      }
      cb00 = nb00; cb01 = nb01; cb10 = nb10; cb11 = nb11;
      p ^= 1;
    }
  }

  // epilogue: C/D map col = lane&15, row = (lane>>4)*4 + reg
#pragma unroll
  for (int i = 0; i < 2; ++i) {
#pragma unroll
    for (int r = 0; r < 4; ++r) {
      const int grow = t0 + wm * 32 + i * 16 + fq * 4 + r;
      if (grow < n_e) {
        const float cw = cw_list[e * T_TOK + grow];
        const int hs = hslot_list[e * T_TOK + grow];
        unsigned short* dst = h_buf + (size_t)hs * IMED + ntile * 64 + wn * 32 + fr;
#pragma unroll
        for (int j = 0; j < 2; ++j) {
          const float v = acc[i][j][r];
          dst[j * 16] = f2bf((v / (1.f + expf(-v))) * cw);
        }
      }
    }
  }
}

// ---------------- MFMA GEMM2, M64 x N64, BK=64 dbuf A-in-LDS (swizzled), B reg-dequant from qk2 ----------------
__global__ __launch_bounds__(256) void mfma_gemm2(
    const unsigned short* __restrict__ h_buf, const unsigned* __restrict__ qk2,
    const int* __restrict__ qz2, const float* __restrict__ sc2,
    const int* __restrict__ counts, const int* __restrict__ hslot_list,
    unsigned short* __restrict__ p_buf) {
  const int e = blockIdx.z;
  const int n_e = counts[e];
  const int t0 = blockIdx.y * 64;
  if (t0 >= n_e) return;
  const int ntile = blockIdx.x;  // 0..15
  const int tid = threadIdx.x;
  const int wave = tid >> 6, lane = tid & 63;
  const int wm = wave & 1, wn = wave >> 1;
  const int fr = lane & 15, fq = lane >> 4;

  __shared__ unsigned short As[2][64 * 64];

  const int arow = tid >> 3;
  const int acb = ((tid & 7) ^ ((tid >> 3) & 7)) * 16;
  const int ha0 = hslot_list[e * T_TOK + min(t0 + arow, n_e - 1)];
  const int ha1 = hslot_list[e * T_TOK + min(t0 + 32 + arow, n_e - 1)];
  const char* ga0 = (const char*)(h_buf + (size_t)ha0 * IMED) + acb;
  const char* ga1 = (const char*)(h_buf + (size_t)ha1 * IMED) + acb;

  auto stage = [&](int b) {
    char* l = (char*)&As[b][0] + wave * 1024;
    async16(ga0, l);
    async16(ga1, l + 4096);
    ga0 += 128; ga1 += 128;
  };

  const int nbase = e * HID + ntile * 64 + wn * 32;
  const unsigned* bl0 = qk2 + (size_t)(nbase >> 4) * 1024 + fq * 16 + fr;  // (IMED/8)*16 = 1024
  const unsigned* bl1 = bl0 + 1024;
  const int shz = ((fr >> 1) & 3) * 4 + (fr & 1) * 16;

  f32x4 acc[2][2];
#pragma unroll
  for (int i = 0; i < 2; ++i)
#pragma unroll
    for (int j = 0; j < 2; ++j) acc[i][j] = (f32x4){0.f, 0.f, 0.f, 0.f};

  stage(0);
  unsigned cb00 = bl0[0], cb01 = bl0[64], cb10 = bl1[0], cb11 = bl1[64];
  int p = 0;
#pragma unroll 1
  for (int g = 0; g < IMED / 128; ++g) {
    const float s0f = sc2[(size_t)g * N2 + nbase + fr];
    const float s1f = sc2[(size_t)g * N2 + nbase + 16 + fr];
    const unsigned zd0 = (unsigned)qz2[(size_t)g * C2 + (nbase >> 3) + (fr >> 3)];
    const unsigned zd1 = (unsigned)qz2[(size_t)g * C2 + 2 + (nbase >> 3) + (fr >> 3)];
    const float w0f = -(float)((zd0 >> shz) & 15u) * s0f;
    const float w1f = -(float)((zd1 >> shz) & 15u) * s1f;
#pragma unroll
    for (int hh = 0; hh < 2; ++hh) {
      const int k0 = g * 128 + hh * 64;
      __syncthreads();
      if (k0 + 64 < IMED) stage(p ^ 1);
      unsigned nb00 = 0, nb01 = 0, nb10 = 0, nb11 = 0;
      if (k0 + 64 < IMED) {
        const unsigned* q0 = bl0 + (k0 + 64) * 2;
        const unsigned* q1 = bl1 + (k0 + 64) * 2;
        nb00 = q0[0]; nb01 = q0[64]; nb10 = q1[0]; nb11 = q1[64];
      }
      const bf16x8 b00 = unpack8(cb00, s0f, w0f);
      const bf16x8 b01 = unpack8(cb01, s0f, w0f);
      const bf16x8 b10 = unpack8(cb10, s1f, w1f);
      const bf16x8 b11 = unpack8(cb11, s1f, w1f);
#pragma unroll
      for (int kk = 0; kk < 2; ++kk) {
        bf16x8 af[2];
#pragma unroll
        for (int i = 0; i < 2; ++i) {
          const int row = wm * 32 + i * 16 + fr;
          af[i] = *reinterpret_cast<const bf16x8*>(
              &As[p][row * 64 + (((kk * 4 + fq) ^ (fr & 7)) * 8)]);
        }
        const bf16x8 b0 = kk ? b01 : b00;
        const bf16x8 b1 = kk ? b11 : b10;
        acc[0][0] = __builtin_amdgcn_mfma_f32_16x16x32_bf16(af[0], b0, acc[0][0], 0, 0, 0);
        acc[0][1] = __builtin_amdgcn_mfma_f32_16x16x32_bf16(af[0], b1, acc[0][1], 0, 0, 0);
        acc[1][0] = __builtin_amdgcn_mfma_f32_16x16x32_bf16(af[1], b0, acc[1][0], 0, 0, 0);
        acc[1][1] = __builtin_amdgcn_mfma_f32_16x16x32_bf16(af[1], b1, acc[1][1], 0, 0, 0);
      }
      cb00 = nb00; cb01 = nb01; cb10 = nb10; cb11 = nb11;
      p ^= 1;
    }
  }

  // epilogue: plain bf16 partial stores (no atomics); every (hslot, col) written once
#pragma unroll
  for (int i = 0; i < 2; ++i) {
#pragma unroll
    for (int r = 0; r < 4; ++r) {
      const int grow = t0 + wm * 32 + i * 16 + fq * 4 + r;
      if (grow < n_e) {
        const int hs = hslot_list[e * T_TOK + grow];
        unsigned short* dst = p_buf + (size_t)hs * HID + ntile * 64 + wn * 32 + fr;
#pragma unroll
        for (int j = 0; j < 2; ++j) dst[j * 16] = f2bf(acc[i][j][r]);
      }
    }
  }
}

// ---------------- Reduce 8 partials per token -> out (fp32, verified R3/R8) ----------------
__global__ __launch_bounds__(256) void reduce_kernel(const unsigned short* __restrict__ p_buf,
                                                     float* __restrict__ out) {
  const int idx = blockIdx.x * 256 + threadIdx.x;
  const int t = idx >> 7;
  const int c0 = (idx & 127) * 8;
  float s[8] = {0.f, 0.f, 0.f, 0.f, 0.f, 0.f, 0.f, 0.f};
#pragma unroll
  for (int k = 0; k < TOPK; ++k) {
    ushortx8 v = *reinterpret_cast<const ushortx8*>(p_buf + ((size_t)t * TOPK + k) * HID + c0);
#pragma unroll
    for (int j = 0; j < 8; ++j) s[j] += bf2f(v[j]);
  }
  float* dst = out + (size_t)t * HID + c0;
  *reinterpret_cast<float4*>(dst) = make_float4(s[0], s[1], s[2], s[3]);
  *reinterpret_cast<float4*>(dst + 4) = make_float4(s[4], s[5], s[6], s[7]);
}

extern "C" void kernel_launch(void* const* d_in, const int* in_sizes, int n_in,
                              void* d_out, int out_size, void* d_ws, size_t ws_size,
                              hipStream_t stream) {
  const float* x      = (const float*)d_in[0];
  const float* gate_w = (const float*)d_in[1];
  const int*   qw1    = (const int*)d_in[2];
  const int*   qz1    = (const int*)d_in[3];
  const float* sc1    = (const float*)d_in[4];
  const int*   qw2    = (const int*)d_in[5];
  const int*   qz2    = (const int*)d_in[6];
  const float* sc2    = (const float*)d_in[7];
  float* out = (float*)d_out;

  // workspace layout
  char* ws = (char*)d_ws;
  int* counts           = (int*)(ws);                        // 256 B
  int* tok_list         = (int*)(ws + 256);                  // 512 KB
  int* hslot_list       = (int*)(ws + 524544);               // 512 KB
  float* cw_list        = (float*)(ws + 1048832);            // 512 KB
  unsigned short* h_buf = (unsigned short*)(ws + 1573120);   // 16.8 MB
  unsigned short* xbf   = (unsigned short*)(ws + 18350336);  // 4.2 MB
  unsigned* qk1         = (unsigned*)(ws + 22544640);        // 16.8 MB (nibbles along K)
  unsigned* qk2         = (unsigned*)(ws + 39321856);        // 16.8 MB
  unsigned short* p_buf = (unsigned short*)(ws + 56099072);  // 33.6 MB

  hipMemsetAsync(counts, 0, 256, stream);

  routing_kernel<<<T_TOK, 256, 0, stream>>>(x, gate_w, counts, tok_list, hslot_list, cw_list, xbf);
  repack_kernel<<<dim3(C1 / 512, HID / 8), 256, 0, stream>>>(qw1, qk1, HID, C1);
  repack_kernel<<<dim3(C2 / 512, IMED / 8), 256, 0, stream>>>(qw2, qk2, IMED, C2);

  mfma_gemm1<<<dim3(IMED / 64, T_TOK / 64, EXP), 256, 0, stream>>>(
      xbf, qk1, qz1, sc1, counts, tok_list, hslot_list, cw_list, h_buf);
  mfma_gemm2<<<dim3(HID / 64, T_TOK / 64, EXP), 256, 0, stream>>>(
      h_buf, qk2, qz2, sc2, counts, hslot_list, p_buf);
  reduce_kernel<<<(T_TOK * HID / 8) / 256, 256, 0, stream>>>(p_buf, out);
}

// Round 6
// 265.537 us; speedup vs baseline: 1.1977x; 1.1003x over previous
//
#include <hip/hip_runtime.h>
#include <hip/hip_bf16.h>

#define T_TOK 2048
#define HID   1024
#define EXP   64
#define TOPK  8
#define IMED  512
#define N1 (EXP * IMED)   // 32768
#define C1 (N1 / 8)       // 4096
#define N2 (EXP * HID)    // 65536
#define C2 (N2 / 8)       // 8192

typedef _Float16 h16x2 __attribute__((ext_vector_type(2)));
typedef _Float16 h16x8 __attribute__((ext_vector_type(8)));
typedef float f32x4 __attribute__((ext_vector_type(4)));
typedef unsigned short ushortx4 __attribute__((ext_vector_type(4)));
typedef unsigned short ushortx8 __attribute__((ext_vector_type(8)));

__constant__ int kShifts[8] = {0, 16, 4, 20, 8, 24, 12, 28};

__device__ __forceinline__ void async16(const void* g, void* l) {
  __builtin_amdgcn_global_load_lds((const __attribute__((address_space(1))) void*)g,
                                   (__attribute__((address_space(3))) void*)l, 16, 0, 0);
}

__device__ __forceinline__ unsigned short f2h(float f) {
  return __builtin_bit_cast(unsigned short, (_Float16)f);
}
__device__ __forceinline__ float h2f(unsigned short b) {
  return (float)__builtin_bit_cast(_Float16, b);
}

// magic fp16 dequant: nibble|0x6400 = fp16(1024+q); (1024+q)-(1024+z) exact; *s.
// q has nibbles pre-interleaved (stored pos order k0,k2,k4,k6,k1,k3,k5,k7) so mask
// extraction yields consecutive-k pairs in MFMA operand dword order.
__device__ __forceinline__ h16x8 unpack8h(unsigned q, h16x2 sh2, h16x2 zh2) {
  union { unsigned u[4]; h16x8 v; } out;
#pragma unroll
  for (int j = 0; j < 4; ++j) {
    const unsigned m = ((q >> (4 * j)) & 0x000F000Fu) | 0x64006400u;
    h16x2 d = __builtin_bit_cast(h16x2, m) - zh2;
    d = d * sh2;
    out.u[j] = __builtin_bit_cast(unsigned, d);
  }
  return out.v;
}

// ---------------- Routing: 256 thr/token, LDS x-row, fused fp16 cast ----------------
__global__ __launch_bounds__(256) void routing_kernel(
    const float* __restrict__ x, const float* __restrict__ gate_w,
    int* __restrict__ counts, int* __restrict__ tok_list,
    int* __restrict__ hslot_list, float* __restrict__ cw_list,
    unsigned short* __restrict__ xh) {
  const int t = blockIdx.x;
  const int tid = threadIdx.x;
  __shared__ float xs[HID];
  __shared__ float part[64][4];

  float4 v = reinterpret_cast<const float4*>(x + (size_t)t * HID)[tid];
  reinterpret_cast<float4*>(xs)[tid] = v;
  ushortx4 o;
  o[0] = f2h(v.x); o[1] = f2h(v.y); o[2] = f2h(v.z); o[3] = f2h(v.w);
  *reinterpret_cast<ushortx4*>(xh + (size_t)t * HID + tid * 4) = o;
  __syncthreads();

  const int e = tid >> 2, seg = tid & 3;
  const float4* gp = reinterpret_cast<const float4*>(gate_w + (size_t)e * HID);
  const float4* xp = reinterpret_cast<const float4*>(xs);
  float acc = 0.f;
#pragma unroll 8
  for (int i = 0; i < 64; ++i) {
    float4 a = xp[i * 4 + seg];
    float4 b = gp[i * 4 + seg];
    acc = fmaf(a.x, b.x, acc);
    acc = fmaf(a.y, b.y, acc);
    acc = fmaf(a.z, b.z, acc);
    acc = fmaf(a.w, b.w, acc);
  }
  part[e][seg] = acc;
  __syncthreads();

  if (tid < 64) {
    float4 p = reinterpret_cast<const float4*>(part)[tid];
    float lg = (p.x + p.y) + (p.z + p.w);

    float m = lg;
    for (int off = 32; off; off >>= 1) m = fmaxf(m, __shfl_xor(m, off));
    float pe = expf(lg - m);
    float s = pe;
    for (int off = 32; off; off >>= 1) s += __shfl_xor(s, off);
    float prob = pe / s;

    float pcur = prob;
    float myv = 0.f;
    int myi = -1;
    float tsum = 0.f;
    for (int k = 0; k < TOPK; ++k) {
      float vv = pcur;
      int idx = tid;
      for (int off = 32; off; off >>= 1) {
        float ov = __shfl_xor(vv, off);
        int oi = __shfl_xor(idx, off);
        if (ov > vv || (ov == vv && oi < idx)) { vv = ov; idx = oi; }
      }
      tsum += vv;
      if (tid == k) { myv = vv; myi = idx; }
      if (tid == idx) pcur = -1.f;
    }

    if (tid < TOPK) {
      float cw = myv / tsum;
      int ex = myi;
      int slot = atomicAdd(&counts[ex], 1);
      tok_list[ex * T_TOK + slot] = t;
      hslot_list[ex * T_TOK + slot] = t * TOPK + tid;
      cw_list[ex * T_TOK + slot] = cw;
    }
  }
}

// ---------------- Repack AWQ nibbles -> qk[nblk][t][fq][fr][2] with k-interleave ----------------
// Output dword (col n, k-octet o): stored nibble pos p holds k-offsets in order
// k0,k2,k4,k6,k1,k3,k5,k7 (pos(r) = (r&1)*4 + (r>>1)).  int2 = octets (t*8+fq, t*8+fq+4).
__global__ __launch_bounds__(256) void repack_kernel(
    const int* __restrict__ qw, unsigned* __restrict__ qk, int K, int C) {
  const int pp = blockIdx.y;            // 0..K/16-1
  const int t = pp >> 2, fq = pp & 3;
  const int c2 = blockIdx.x * 512 + threadIdx.x * 2;  // even qw dword-col
  const int nblk = c2 >> 1;
  unsigned o0[16], o1[16];
#pragma unroll
  for (int i = 0; i < 16; ++i) { o0[i] = 0u; o1[i] = 0u; }
  const int k0a = t * 64 + fq * 8;
  const int k0b = t * 64 + (fq + 4) * 8;
#pragma unroll
  for (int r = 0; r < 8; ++r) {
    const int2 va = *reinterpret_cast<const int2*>(qw + (size_t)(k0a + r) * C + c2);
    const int2 vb = *reinterpret_cast<const int2*>(qw + (size_t)(k0b + r) * C + c2);
    const int outsh = (r & 1) * 16 + (r >> 1) * 4;
    const unsigned qa[2] = {(unsigned)va.x, (unsigned)va.y};
    const unsigned qb[2] = {(unsigned)vb.x, (unsigned)vb.y};
#pragma unroll
    for (int ci = 0; ci < 2; ++ci) {
#pragma unroll
      for (int j = 0; j < 8; ++j) {
        const int sh = kShifts[j];
        o0[ci * 8 + j] |= ((qa[ci] >> sh) & 0xFu) << outsh;
        o1[ci * 8 + j] |= ((qb[ci] >> sh) & 0xFu) << outsh;
      }
    }
  }
  unsigned* dst = qk + (size_t)nblk * 2 * K + t * 128 + fq * 32;
#pragma unroll
  for (int idx = 0; idx < 16; ++idx)
    *reinterpret_cast<uint2*>(dst + idx * 2) = make_uint2(o0[idx], o1[idx]);
}

// ---------------- MFMA GEMM1: M64xN64, waves 1x4 (wave = 64Mx16N), BK=64, fp16 magic dequant ----------------
__global__ __launch_bounds__(256) void mfma_gemm1(
    const unsigned short* __restrict__ xh, const unsigned* __restrict__ qk1,
    const int* __restrict__ qz1, const float* __restrict__ sc1,
    const int* __restrict__ counts, const int* __restrict__ tok_list,
    const int* __restrict__ hslot_list, const float* __restrict__ cw_list,
    unsigned short* __restrict__ h_buf) {
  const int e = blockIdx.z;
  const int n_e = counts[e];
  const int t0 = blockIdx.y * 64;
  if (t0 >= n_e) return;
  const int ntile = blockIdx.x;  // 0..7
  const int tid = threadIdx.x;
  const int wave = tid >> 6, lane = tid & 63;
  const int fr = lane & 15, fq = lane >> 4;

  __shared__ unsigned short As[2][64 * 64];  // 2 x 8KB, XOR-swizzled source (verified R4)

  const int arow = tid >> 3;                            // 0..31
  const int acb = ((tid & 7) ^ ((tid >> 3) & 7)) * 16;  // pre-swizzled byte col
  const int ta0 = tok_list[e * T_TOK + min(t0 + arow, n_e - 1)];
  const int ta1 = tok_list[e * T_TOK + min(t0 + 32 + arow, n_e - 1)];
  const char* ga0 = (const char*)(xh + (size_t)ta0 * HID) + acb;
  const char* ga1 = (const char*)(xh + (size_t)ta1 * HID) + acb;

  auto stage = [&](int b) {
    char* l = (char*)&As[b][0] + wave * 1024;  // + HW lane*16
    async16(ga0, l);
    async16(ga1, l + 4096);
    ga0 += 128; ga1 += 128;
  };

  // B: qk1[nblk][t][fq][fr][2]; wave owns 16 cols, lane col = nbase + fr
  const int nbase = e * IMED + ntile * 64 + wave * 16;
  const unsigned* bp = qk1 + (size_t)(nbase >> 4) * (2 * HID) + fq * 32 + fr * 2;
  const int col = nbase + fr;
  const int shz = ((fr >> 1) & 3) * 4 + (fr & 1) * 16;  // kShifts[fr&7]

  f32x4 acc[4];
#pragma unroll
  for (int i = 0; i < 4; ++i) acc[i] = (f32x4){0.f, 0.f, 0.f, 0.f};

  stage(0);
  uint2 qcur = *reinterpret_cast<const uint2*>(bp);
  float s_cur = sc1[col];
  unsigned zd_cur = (unsigned)qz1[col >> 3];
  int p = 0;
#pragma unroll 1
  for (int g = 0; g < HID / 128; ++g) {
    const unsigned shb = (unsigned)f2h(s_cur);
    const h16x2 sh2 = __builtin_bit_cast(h16x2, shb | (shb << 16));
    const unsigned zb = 0x6400u | ((zd_cur >> shz) & 15u);
    const h16x2 zh2 = __builtin_bit_cast(h16x2, zb | (zb << 16));
    float s_nxt = 0.f; unsigned zd_nxt = 0u;
#pragma unroll
    for (int hh = 0; hh < 2; ++hh) {
      const int t = g * 2 + hh;
      __syncthreads();  // As[p] ready
      if (t + 1 < HID / 64) stage(p ^ 1);
      uint2 qnext = make_uint2(0u, 0u);
      if (t + 1 < HID / 64) qnext = *reinterpret_cast<const uint2*>(bp + (t + 1) * 128);
      if (hh == 1 && g + 1 < HID / 128) {
        s_nxt = sc1[(size_t)(g + 1) * N1 + col];
        zd_nxt = (unsigned)qz1[(size_t)(g + 1) * C1 + (col >> 3)];
      }
      const h16x8 b0 = unpack8h(qcur.x, sh2, zh2);
      const h16x8 b1 = unpack8h(qcur.y, sh2, zh2);
#pragma unroll
      for (int kk = 0; kk < 2; ++kk) {
        const h16x8 bb = kk ? b1 : b0;
#pragma unroll
        for (int i = 0; i < 4; ++i) {
          const int row = i * 16 + fr;
          const h16x8 a = *reinterpret_cast<const h16x8*>(
              &As[p][row * 64 + (((kk * 4 + fq) ^ (fr & 7)) * 8)]);
          acc[i] = __builtin_amdgcn_mfma_f32_16x16x32_f16(a, bb, acc[i], 0, 0, 0);
        }
      }
      qcur = qnext; p ^= 1;
    }
    s_cur = s_nxt; zd_cur = zd_nxt;
  }

  // epilogue: C/D map col = lane&15, row = (lane>>4)*4 + reg
#pragma unroll
  for (int i = 0; i < 4; ++i) {
#pragma unroll
    for (int r = 0; r < 4; ++r) {
      const int grow = t0 + i * 16 + fq * 4 + r;
      if (grow < n_e) {
        const float cw = cw_list[e * T_TOK + grow];
        const int hs = hslot_list[e * T_TOK + grow];
        const float v = acc[i][r];
        h_buf[(size_t)hs * IMED + ntile * 64 + wave * 16 + fr] =
            f2h((v / (1.f + expf(-v))) * cw);
      }
    }
  }
}

// ---------------- MFMA GEMM2: M64xN64, waves 1x4, BK=64, fp16 magic dequant ----------------
__global__ __launch_bounds__(256) void mfma_gemm2(
    const unsigned short* __restrict__ h_buf, const unsigned* __restrict__ qk2,
    const int* __restrict__ qz2, const float* __restrict__ sc2,
    const int* __restrict__ counts, const int* __restrict__ hslot_list,
    unsigned short* __restrict__ p_buf) {
  const int e = blockIdx.z;
  const int n_e = counts[e];
  const int t0 = blockIdx.y * 64;
  if (t0 >= n_e) return;
  const int ntile = blockIdx.x;  // 0..15
  const int tid = threadIdx.x;
  const int wave = tid >> 6, lane = tid & 63;
  const int fr = lane & 15, fq = lane >> 4;

  __shared__ unsigned short As[2][64 * 64];

  const int arow = tid >> 3;
  const int acb = ((tid & 7) ^ ((tid >> 3) & 7)) * 16;
  const int ha0 = hslot_list[e * T_TOK + min(t0 + arow, n_e - 1)];
  const int ha1 = hslot_list[e * T_TOK + min(t0 + 32 + arow, n_e - 1)];
  const char* ga0 = (const char*)(h_buf + (size_t)ha0 * IMED) + acb;
  const char* ga1 = (const char*)(h_buf + (size_t)ha1 * IMED) + acb;

  auto stage = [&](int b) {
    char* l = (char*)&As[b][0] + wave * 1024;
    async16(ga0, l);
    async16(ga1, l + 4096);
    ga0 += 128; ga1 += 128;
  };

  const int nbase = e * HID + ntile * 64 + wave * 16;
  const unsigned* bp = qk2 + (size_t)(nbase >> 4) * (2 * IMED) + fq * 32 + fr * 2;
  const int col = nbase + fr;
  const int shz = ((fr >> 1) & 3) * 4 + (fr & 1) * 16;

  f32x4 acc[4];
#pragma unroll
  for (int i = 0; i < 4; ++i) acc[i] = (f32x4){0.f, 0.f, 0.f, 0.f};

  stage(0);
  uint2 qcur = *reinterpret_cast<const uint2*>(bp);
  float s_cur = sc2[col];
  unsigned zd_cur = (unsigned)qz2[col >> 3];
  int p = 0;
#pragma unroll 1
  for (int g = 0; g < IMED / 128; ++g) {
    const unsigned shb = (unsigned)f2h(s_cur);
    const h16x2 sh2 = __builtin_bit_cast(h16x2, shb | (shb << 16));
    const unsigned zb = 0x6400u | ((zd_cur >> shz) & 15u);
    const h16x2 zh2 = __builtin_bit_cast(h16x2, zb | (zb << 16));
    float s_nxt = 0.f; unsigned zd_nxt = 0u;
#pragma unroll
    for (int hh = 0; hh < 2; ++hh) {
      const int t = g * 2 + hh;
      __syncthreads();
      if (t + 1 < IMED / 64) stage(p ^ 1);
      uint2 qnext = make_uint2(0u, 0u);
      if (t + 1 < IMED / 64) qnext = *reinterpret_cast<const uint2*>(bp + (t + 1) * 128);
      if (hh == 1 && g + 1 < IMED / 128) {
        s_nxt = sc2[(size_t)(g + 1) * N2 + col];
        zd_nxt = (unsigned)qz2[(size_t)(g + 1) * C2 + (col >> 3)];
      }
      const h16x8 b0 = unpack8h(qcur.x, sh2, zh2);
      const h16x8 b1 = unpack8h(qcur.y, sh2, zh2);
#pragma unroll
      for (int kk = 0; kk < 2; ++kk) {
        const h16x8 bb = kk ? b1 : b0;
#pragma unroll
        for (int i = 0; i < 4; ++i) {
          const int row = i * 16 + fr;
          const h16x8 a = *reinterpret_cast<const h16x8*>(
              &As[p][row * 64 + (((kk * 4 + fq) ^ (fr & 7)) * 8)]);
          acc[i] = __builtin_amdgcn_mfma_f32_16x16x32_f16(a, bb, acc[i], 0, 0, 0);
        }
      }
      qcur = qnext; p ^= 1;
    }
    s_cur = s_nxt; zd_cur = zd_nxt;
  }

  // epilogue: plain fp16 partial stores; every (hslot, col) written once
#pragma unroll
  for (int i = 0; i < 4; ++i) {
#pragma unroll
    for (int r = 0; r < 4; ++r) {
      const int grow = t0 + i * 16 + fq * 4 + r;
      if (grow < n_e) {
        const int hs = hslot_list[e * T_TOK + grow];
        p_buf[(size_t)hs * HID + ntile * 64 + wave * 16 + fr] = f2h(acc[i][r]);
      }
    }
  }
}

// ---------------- Reduce 8 partials per token -> out (fp32) ----------------
__global__ __launch_bounds__(256) void reduce_kernel(const unsigned short* __restrict__ p_buf,
                                                     float* __restrict__ out) {
  const int idx = blockIdx.x * 256 + threadIdx.x;
  const int t = idx >> 7;
  const int c0 = (idx & 127) * 8;
  float s[8] = {0.f, 0.f, 0.f, 0.f, 0.f, 0.f, 0.f, 0.f};
#pragma unroll
  for (int k = 0; k < TOPK; ++k) {
    ushortx8 v = *reinterpret_cast<const ushortx8*>(p_buf + ((size_t)t * TOPK + k) * HID + c0);
#pragma unroll
    for (int j = 0; j < 8; ++j) s[j] += h2f(v[j]);
  }
  float* dst = out + (size_t)t * HID + c0;
  *reinterpret_cast<float4*>(dst) = make_float4(s[0], s[1], s[2], s[3]);
  *reinterpret_cast<float4*>(dst + 4) = make_float4(s[4], s[5], s[6], s[7]);
}

extern "C" void kernel_launch(void* const* d_in, const int* in_sizes, int n_in,
                              void* d_out, int out_size, void* d_ws, size_t ws_size,
                              hipStream_t stream) {
  const float* x      = (const float*)d_in[0];
  const float* gate_w = (const float*)d_in[1];
  const int*   qw1    = (const int*)d_in[2];
  const int*   qz1    = (const int*)d_in[3];
  const float* sc1    = (const float*)d_in[4];
  const int*   qw2    = (const int*)d_in[5];
  const int*   qz2    = (const int*)d_in[6];
  const float* sc2    = (const float*)d_in[7];
  float* out = (float*)d_out;

  // workspace layout
  char* ws = (char*)d_ws;
  int* counts           = (int*)(ws);                        // 256 B
  int* tok_list         = (int*)(ws + 256);                  // 512 KB
  int* hslot_list       = (int*)(ws + 524544);               // 512 KB
  float* cw_list        = (float*)(ws + 1048832);            // 512 KB
  unsigned short* h_buf = (unsigned short*)(ws + 1573120);   // 16.8 MB
  unsigned short* xh    = (unsigned short*)(ws + 18350336);  // 4.2 MB
  unsigned* qk1         = (unsigned*)(ws + 22544640);        // 16.8 MB (nibbles along K, interleaved)
  unsigned* qk2         = (unsigned*)(ws + 39321856);        // 16.8 MB
  unsigned short* p_buf = (unsigned short*)(ws + 56099072);  // 33.6 MB

  hipMemsetAsync(counts, 0, 256, stream);

  routing_kernel<<<T_TOK, 256, 0, stream>>>(x, gate_w, counts, tok_list, hslot_list, cw_list, xh);
  repack_kernel<<<dim3(C1 / 512, HID / 16), 256, 0, stream>>>(qw1, qk1, HID, C1);
  repack_kernel<<<dim3(C2 / 512, IMED / 16), 256, 0, stream>>>(qw2, qk2, IMED, C2);

  mfma_gemm1<<<dim3(IMED / 64, T_TOK / 64, EXP), 256, 0, stream>>>(
      xh, qk1, qz1, sc1, counts, tok_list, hslot_list, cw_list, h_buf);
  mfma_gemm2<<<dim3(HID / 64, T_TOK / 64, EXP), 256, 0, stream>>>(
      h_buf, qk2, qz2, sc2, counts, hslot_list, p_buf);
  reduce_kernel<<<(T_TOK * HID / 8) / 256, 256, 0, stream>>>(p_buf, out);
}

// Round 8
// 254.455 us; speedup vs baseline: 1.2499x; 1.0436x over previous
//
#include <hip/hip_runtime.h>
#include <hip/hip_bf16.h>

#define T_TOK 2048
#define HID   1024
#define EXP   64
#define TOPK  8
#define IMED  512
#define N1 (EXP * IMED)   // 32768
#define C1 (N1 / 8)       // 4096
#define N2 (EXP * HID)    // 65536
#define C2 (N2 / 8)       // 8192

typedef _Float16 h16x2 __attribute__((ext_vector_type(2)));
typedef _Float16 h16x8 __attribute__((ext_vector_type(8)));
typedef float f32x4 __attribute__((ext_vector_type(4)));
typedef unsigned short ushortx4 __attribute__((ext_vector_type(4)));
typedef unsigned short ushortx8 __attribute__((ext_vector_type(8)));

__constant__ int kShifts[8] = {0, 16, 4, 20, 8, 24, 12, 28};

__device__ __forceinline__ void async16(const void* g, void* l) {
  __builtin_amdgcn_global_load_lds((const __attribute__((address_space(1))) void*)g,
                                   (__attribute__((address_space(3))) void*)l, 16, 0, 0);
}

__device__ __forceinline__ unsigned short f2h(float f) {
  return __builtin_bit_cast(unsigned short, (_Float16)f);
}
__device__ __forceinline__ float h2f(unsigned short b) {
  return (float)__builtin_bit_cast(_Float16, b);
}

// magic fp16 dequant: nibble|0x6400 = fp16(1024+q); (1024+q)-(1024+z) exact; *s.
// q has nibbles pre-interleaved (stored pos order k0,k2,k4,k6,k1,k3,k5,k7) so mask
// extraction yields consecutive-k pairs in MFMA operand dword order.
__device__ __forceinline__ h16x8 unpack8h(unsigned q, h16x2 sh2, h16x2 zh2) {
  union { unsigned u[4]; h16x8 v; } out;
#pragma unroll
  for (int j = 0; j < 4; ++j) {
    const unsigned m = ((q >> (4 * j)) & 0x000F000Fu) | 0x64006400u;
    h16x2 d = __builtin_bit_cast(h16x2, m) - zh2;
    d = d * sh2;
    out.u[j] = __builtin_bit_cast(unsigned, d);
  }
  return out.v;
}

// ---------------- Cast x -> fp16 (streaming) ----------------
__global__ __launch_bounds__(256) void cast_x_kernel(const float* __restrict__ x,
                                                     unsigned short* __restrict__ xh) {
  const int i = (blockIdx.x * 256 + threadIdx.x) * 4;
  float4 v = *reinterpret_cast<const float4*>(x + i);
  ushortx4 o;
  o[0] = f2h(v.x); o[1] = f2h(v.y); o[2] = f2h(v.z); o[3] = f2h(v.w);
  *reinterpret_cast<ushortx4*>(xh + i) = o;
}

// ---------------- Logits (f32, split-K): partial[ks][t][e] = x[t,k-slice] . gate[e,k-slice] ----------------
// grid (32 token-tiles, 8 k-splits); LDS tiles [64][128] f32 with float4-block XOR swizzle
// c' = c ^ ((row>>2)&7): expert reads (row stride 4, 512B) go 8-way-conflict -> 2-way (free).
__global__ __launch_bounds__(256) void logits_f32_kernel(
    const float* __restrict__ x, const float* __restrict__ gate_w,
    float* __restrict__ partial) {
  const int t0 = blockIdx.x * 64;
  const int k0 = blockIdx.y * 128;
  const int tid = threadIdx.x;

  __shared__ float xs[64][128];
  __shared__ float gs[64][128];

  const int lrow = tid >> 5;        // 0..7
  const int cblk = tid & 31;        // float4 block 0..31
#pragma unroll
  for (int r = 0; r < 8; ++r) {
    const int row = r * 8 + lrow;
    const int sc = (cblk ^ ((row >> 2) & 7)) * 4;  // swizzled dword col
    float4 xv = *reinterpret_cast<const float4*>(x + (size_t)(t0 + row) * HID + k0 + cblk * 4);
    float4 gv = *reinterpret_cast<const float4*>(gate_w + (size_t)row * HID + k0 + cblk * 4);
    *reinterpret_cast<float4*>(&xs[row][sc]) = xv;
    *reinterpret_cast<float4*>(&gs[row][sc]) = gv;
  }
  __syncthreads();

  const int tg = (tid >> 4) * 4;   // token group base
  const int eg = (tid & 15) * 4;   // expert group base
  const int xsw = (tid >> 4) & 7;  // xor for xs rows tg..tg+3 ((tg+i)>>2 = tid>>4)
  const int gsw = tid & 7;         // xor for gs rows eg..eg+3 ((eg+j)>>2 = tid&15)
  float acc[4][4] = {{0.f}};
#pragma unroll 8
  for (int k = 0; k < 128; k += 4) {
    const int c = k >> 2;
    float4 a[4], b[4];
#pragma unroll
    for (int i = 0; i < 4; ++i)
      a[i] = *reinterpret_cast<const float4*>(&xs[tg + i][(c ^ xsw) * 4]);
#pragma unroll
    for (int j = 0; j < 4; ++j)
      b[j] = *reinterpret_cast<const float4*>(&gs[eg + j][(c ^ gsw) * 4]);
#pragma unroll
    for (int i = 0; i < 4; ++i)
#pragma unroll
      for (int j = 0; j < 4; ++j) {
        acc[i][j] = fmaf(a[i].x, b[j].x, acc[i][j]);
        acc[i][j] = fmaf(a[i].y, b[j].y, acc[i][j]);
        acc[i][j] = fmaf(a[i].z, b[j].z, acc[i][j]);
        acc[i][j] = fmaf(a[i].w, b[j].w, acc[i][j]);
      }
  }
  float* dst = partial + ((size_t)blockIdx.y * T_TOK + t0) * EXP;
#pragma unroll
  for (int i = 0; i < 4; ++i)
    *reinterpret_cast<float4*>(dst + (tg + i) * EXP + eg) =
        make_float4(acc[i][0], acc[i][1], acc[i][2], acc[i][3]);
}

// ---------------- Top-k: one wave per token; folds the 8-way k-split sum ----------------
__global__ __launch_bounds__(256) void topk_kernel(
    const float* __restrict__ partial, int* __restrict__ counts,
    int* __restrict__ tok_list, int* __restrict__ hslot_list,
    float* __restrict__ cw_list) {
  const int wave = threadIdx.x >> 6, lane = threadIdx.x & 63;
  const int t = blockIdx.x * 4 + wave;
  float lg = 0.f;
#pragma unroll
  for (int s = 0; s < 8; ++s)
    lg += partial[((size_t)s * T_TOK + t) * EXP + lane];

  float m = lg;
  for (int off = 32; off; off >>= 1) m = fmaxf(m, __shfl_xor(m, off));
  float pe = expf(lg - m);
  float s = pe;
  for (int off = 32; off; off >>= 1) s += __shfl_xor(s, off);
  float prob = pe / s;

  float pcur = prob;
  float myv = 0.f;
  int myi = -1;
  float tsum = 0.f;
  for (int k = 0; k < TOPK; ++k) {
    float vv = pcur;
    int idx = lane;
    for (int off = 32; off; off >>= 1) {
      float ov = __shfl_xor(vv, off);
      int oi = __shfl_xor(idx, off);
      if (ov > vv || (ov == vv && oi < idx)) { vv = ov; idx = oi; }
    }
    tsum += vv;
    if (lane == k) { myv = vv; myi = idx; }
    if (lane == idx) pcur = -1.f;
  }

  if (lane < TOPK) {
    const float cw = myv / tsum;
    const int ex = myi;
    const int slot = atomicAdd(&counts[ex], 1);
    tok_list[ex * T_TOK + slot] = t;
    hslot_list[ex * T_TOK + slot] = t * TOPK + lane;
    cw_list[ex * T_TOK + slot] = cw;
  }
}

// ---------------- Repack AWQ nibbles -> qk[nblk][t][fq][fr][2] with k-interleave ----------------
// Output dword (col n, k-octet o): stored nibble pos p holds k-offsets in order
// k0,k2,k4,k6,k1,k3,k5,k7 (pos(r) = (r&1)*4 + (r>>1)).  int2 = octets (t*8+fq, t*8+fq+4).
__global__ __launch_bounds__(256) void repack_kernel(
    const int* __restrict__ qw, unsigned* __restrict__ qk, int K, int C) {
  const int pp = blockIdx.y;            // 0..K/16-1
  const int t = pp >> 2, fq = pp & 3;
  const int c2 = blockIdx.x * 512 + threadIdx.x * 2;  // even qw dword-col
  const int nblk = c2 >> 1;
  unsigned o0[16], o1[16];
#pragma unroll
  for (int i = 0; i < 16; ++i) { o0[i] = 0u; o1[i] = 0u; }
  const int k0a = t * 64 + fq * 8;
  const int k0b = t * 64 + (fq + 4) * 8;
#pragma unroll
  for (int r = 0; r < 8; ++r) {
    const int2 va = *reinterpret_cast<const int2*>(qw + (size_t)(k0a + r) * C + c2);
    const int2 vb = *reinterpret_cast<const int2*>(qw + (size_t)(k0b + r) * C + c2);
    const int outsh = (r & 1) * 16 + (r >> 1) * 4;
    const unsigned qa[2] = {(unsigned)va.x, (unsigned)va.y};
    const unsigned qb[2] = {(unsigned)vb.x, (unsigned)vb.y};
#pragma unroll
    for (int ci = 0; ci < 2; ++ci) {
#pragma unroll
      for (int j = 0; j < 8; ++j) {
        const int sh = kShifts[j];
        o0[ci * 8 + j] |= ((qa[ci] >> sh) & 0xFu) << outsh;
        o1[ci * 8 + j] |= ((qb[ci] >> sh) & 0xFu) << outsh;
      }
    }
  }
  unsigned* dst = qk + (size_t)nblk * 2 * K + t * 128 + fq * 32;
#pragma unroll
  for (int idx = 0; idx < 16; ++idx)
    *reinterpret_cast<uint2*>(dst + idx * 2) = make_uint2(o0[idx], o1[idx]);
}

// ---------------- MFMA GEMM1: M64xN64, waves 1x4 (wave = 64Mx16N), BK=64, fp16 magic dequant ----------------
__global__ __launch_bounds__(256) void mfma_gemm1(
    const unsigned short* __restrict__ xh, const unsigned* __restrict__ qk1,
    const int* __restrict__ qz1, const float* __restrict__ sc1,
    const int* __restrict__ counts, const int* __restrict__ tok_list,
    const int* __restrict__ hslot_list, const float* __restrict__ cw_list,
    unsigned short* __restrict__ h_buf) {
  const int e = blockIdx.z;
  const int n_e = counts[e];
  const int t0 = blockIdx.y * 64;
  if (t0 >= n_e) return;
  const int ntile = blockIdx.x;  // 0..7
  const int tid = threadIdx.x;
  const int wave = tid >> 6, lane = tid & 63;
  const int fr = lane & 15, fq = lane >> 4;

  __shared__ unsigned short As[2][64 * 64];  // 2 x 8KB, XOR-swizzled source (verified R4)

  const int arow = tid >> 3;                            // 0..31
  const int acb = ((tid & 7) ^ ((tid >> 3) & 7)) * 16;  // pre-swizzled byte col
  const int ta0 = tok_list[e * T_TOK + min(t0 + arow, n_e - 1)];
  const int ta1 = tok_list[e * T_TOK + min(t0 + 32 + arow, n_e - 1)];
  const char* ga0 = (const char*)(xh + (size_t)ta0 * HID) + acb;
  const char* ga1 = (const char*)(xh + (size_t)ta1 * HID) + acb;

  auto stage = [&](int b) {
    char* l = (char*)&As[b][0] + wave * 1024;  // + HW lane*16
    async16(ga0, l);
    async16(ga1, l + 4096);
    ga0 += 128; ga1 += 128;
  };

  // B: qk1[nblk][t][fq][fr][2]; wave owns 16 cols, lane col = nbase + fr
  const int nbase = e * IMED + ntile * 64 + wave * 16;
  const unsigned* bp = qk1 + (size_t)(nbase >> 4) * (2 * HID) + fq * 32 + fr * 2;
  const int col = nbase + fr;
  const int shz = ((fr >> 1) & 3) * 4 + (fr & 1) * 16;  // kShifts[fr&7]

  f32x4 acc[4];
#pragma unroll
  for (int i = 0; i < 4; ++i) acc[i] = (f32x4){0.f, 0.f, 0.f, 0.f};

  stage(0);
  uint2 qcur = *reinterpret_cast<const uint2*>(bp);
  float s_cur = sc1[col];
  unsigned zd_cur = (unsigned)qz1[col >> 3];
  int p = 0;
#pragma unroll 1
  for (int g = 0; g < HID / 128; ++g) {
    const unsigned shb = (unsigned)f2h(s_cur);
    const h16x2 sh2 = __builtin_bit_cast(h16x2, shb | (shb << 16));
    const unsigned zb = 0x6400u | ((zd_cur >> shz) & 15u);
    const h16x2 zh2 = __builtin_bit_cast(h16x2, zb | (zb << 16));
    float s_nxt = 0.f; unsigned zd_nxt = 0u;
#pragma unroll
    for (int hh = 0; hh < 2; ++hh) {
      const int t = g * 2 + hh;
      __syncthreads();  // As[p] ready
      if (t + 1 < HID / 64) stage(p ^ 1);
      uint2 qnext = make_uint2(0u, 0u);
      if (t + 1 < HID / 64) qnext = *reinterpret_cast<const uint2*>(bp + (t + 1) * 128);
      if (hh == 1 && g + 1 < HID / 128) {
        s_nxt = sc1[(size_t)(g + 1) * N1 + col];
        zd_nxt = (unsigned)qz1[(size_t)(g + 1) * C1 + (col >> 3)];
      }
      const h16x8 b0 = unpack8h(qcur.x, sh2, zh2);
      const h16x8 b1 = unpack8h(qcur.y, sh2, zh2);
#pragma unroll
      for (int kk = 0; kk < 2; ++kk) {
        const h16x8 bb = kk ? b1 : b0;
#pragma unroll
        for (int i = 0; i < 4; ++i) {
          const int row = i * 16 + fr;
          const h16x8 a = *reinterpret_cast<const h16x8*>(
              &As[p][row * 64 + (((kk * 4 + fq) ^ (fr & 7)) * 8)]);
          acc[i] = __builtin_amdgcn_mfma_f32_16x16x32_f16(a, bb, acc[i], 0, 0, 0);
        }
      }
      qcur = qnext; p ^= 1;
    }
    s_cur = s_nxt; zd_cur = zd_nxt;
  }

  // epilogue: C/D map col = lane&15, row = (lane>>4)*4 + reg
#pragma unroll
  for (int i = 0; i < 4; ++i) {
#pragma unroll
    for (int r = 0; r < 4; ++r) {
      const int grow = t0 + i * 16 + fq * 4 + r;
      if (grow < n_e) {
        const float cw = cw_list[e * T_TOK + grow];
        const int hs = hslot_list[e * T_TOK + grow];
        const float v = acc[i][r];
        h_buf[(size_t)hs * IMED + ntile * 64 + wave * 16 + fr] =
            f2h((v / (1.f + expf(-v))) * cw);
      }
    }
  }
}

// ---------------- MFMA GEMM2: M64xN64, waves 1x4, BK=64, fp16 magic dequant ----------------
__global__ __launch_bounds__(256) void mfma_gemm2(
    const unsigned short* __restrict__ h_buf, const unsigned* __restrict__ qk2,
    const int* __restrict__ qz2, const float* __restrict__ sc2,
    const int* __restrict__ counts, const int* __restrict__ hslot_list,
    unsigned short* __restrict__ p_buf) {
  const int e = blockIdx.z;
  const int n_e = counts[e];
  const int t0 = blockIdx.y * 64;
  if (t0 >= n_e) return;
  const int ntile = blockIdx.x;  // 0..15
  const int tid = threadIdx.x;
  const int wave = tid >> 6, lane = tid & 63;
  const int fr = lane & 15, fq = lane >> 4;

  __shared__ unsigned short As[2][64 * 64];

  const int arow = tid >> 3;
  const int acb = ((tid & 7) ^ ((tid >> 3) & 7)) * 16;
  const int ha0 = hslot_list[e * T_TOK + min(t0 + arow, n_e - 1)];
  const int ha1 = hslot_list[e * T_TOK + min(t0 + 32 + arow, n_e - 1)];
  const char* ga0 = (const char*)(h_buf + (size_t)ha0 * IMED) + acb;
  const char* ga1 = (const char*)(h_buf + (size_t)ha1 * IMED) + acb;

  auto stage = [&](int b) {
    char* l = (char*)&As[b][0] + wave * 1024;
    async16(ga0, l);
    async16(ga1, l + 4096);
    ga0 += 128; ga1 += 128;
  };

  const int nbase = e * HID + ntile * 64 + wave * 16;
  const unsigned* bp = qk2 + (size_t)(nbase >> 4) * (2 * IMED) + fq * 32 + fr * 2;
  const int col = nbase + fr;
  const int shz = ((fr >> 1) & 3) * 4 + (fr & 1) * 16;

  f32x4 acc[4];
#pragma unroll
  for (int i = 0; i < 4; ++i) acc[i] = (f32x4){0.f, 0.f, 0.f, 0.f};

  stage(0);
  uint2 qcur = *reinterpret_cast<const uint2*>(bp);
  float s_cur = sc2[col];
  unsigned zd_cur = (unsigned)qz2[col >> 3];
  int p = 0;
#pragma unroll 1
  for (int g = 0; g < IMED / 128; ++g) {
    const unsigned shb = (unsigned)f2h(s_cur);
    const h16x2 sh2 = __builtin_bit_cast(h16x2, shb | (shb << 16));
    const unsigned zb = 0x6400u | ((zd_cur >> shz) & 15u);
    const h16x2 zh2 = __builtin_bit_cast(h16x2, zb | (zb << 16));
    float s_nxt = 0.f; unsigned zd_nxt = 0u;
#pragma unroll
    for (int hh = 0; hh < 2; ++hh) {
      const int t = g * 2 + hh;
      __syncthreads();
      if (t + 1 < IMED / 64) stage(p ^ 1);
      uint2 qnext = make_uint2(0u, 0u);
      if (t + 1 < IMED / 64) qnext = *reinterpret_cast<const uint2*>(bp + (t + 1) * 128);
      if (hh == 1 && g + 1 < IMED / 128) {
        s_nxt = sc2[(size_t)(g + 1) * N2 + col];
        zd_nxt = (unsigned)qz2[(size_t)(g + 1) * C2 + (col >> 3)];
      }
      const h16x8 b0 = unpack8h(qcur.x, sh2, zh2);
      const h16x8 b1 = unpack8h(qcur.y, sh2, zh2);
#pragma unroll
      for (int kk = 0; kk < 2; ++kk) {
        const h16x8 bb = kk ? b1 : b0;
#pragma unroll
        for (int i = 0; i < 4; ++i) {
          const int row = i * 16 + fr;
          const h16x8 a = *reinterpret_cast<const h16x8*>(
              &As[p][row * 64 + (((kk * 4 + fq) ^ (fr & 7)) * 8)]);
          acc[i] = __builtin_amdgcn_mfma_f32_16x16x32_f16(a, bb, acc[i], 0, 0, 0);
        }
      }
      qcur = qnext; p ^= 1;
    }
    s_cur = s_nxt; zd_cur = zd_nxt;
  }

  // epilogue: plain fp16 partial stores; every (hslot, col) written once
#pragma unroll
  for (int i = 0; i < 4; ++i) {
#pragma unroll
    for (int r = 0; r < 4; ++r) {
      const int grow = t0 + i * 16 + fq * 4 + r;
      if (grow < n_e) {
        const int hs = hslot_list[e * T_TOK + grow];
        p_buf[(size_t)hs * HID + ntile * 64 + wave * 16 + fr] = f2h(acc[i][r]);
      }
    }
  }
}

// ---------------- Reduce 8 partials per token -> out (fp32) ----------------
__global__ __launch_bounds__(256) void reduce_kernel(const unsigned short* __restrict__ p_buf,
                                                     float* __restrict__ out) {
  const int idx = blockIdx.x * 256 + threadIdx.x;
  const int t = idx >> 7;
  const int c0 = (idx & 127) * 8;
  float s[8] = {0.f, 0.f, 0.f, 0.f, 0.f, 0.f, 0.f, 0.f};
#pragma unroll
  for (int k = 0; k < TOPK; ++k) {
    ushortx8 v = *reinterpret_cast<const ushortx8*>(p_buf + ((size_t)t * TOPK + k) * HID + c0);
#pragma unroll
    for (int j = 0; j < 8; ++j) s[j] += h2f(v[j]);
  }
  float* dst = out + (size_t)t * HID + c0;
  *reinterpret_cast<float4*>(dst) = make_float4(s[0], s[1], s[2], s[3]);
  *reinterpret_cast<float4*>(dst + 4) = make_float4(s[4], s[5], s[6], s[7]);
}

extern "C" void kernel_launch(void* const* d_in, const int* in_sizes, int n_in,
                              void* d_out, int out_size, void* d_ws, size_t ws_size,
                              hipStream_t stream) {
  const float* x      = (const float*)d_in[0];
  const float* gate_w = (const float*)d_in[1];
  const int*   qw1    = (const int*)d_in[2];
  const int*   qz1    = (const int*)d_in[3];
  const float* sc1    = (const float*)d_in[4];
  const int*   qw2    = (const int*)d_in[5];
  const int*   qz2    = (const int*)d_in[6];
  const float* sc2    = (const float*)d_in[7];
  float* out = (float*)d_out;

  // workspace layout
  char* ws = (char*)d_ws;
  int* counts           = (int*)(ws);                        // 256 B
  int* tok_list         = (int*)(ws + 256);                  // 512 KB
  int* hslot_list       = (int*)(ws + 524544);               // 512 KB
  float* cw_list        = (float*)(ws + 1048832);            // 512 KB
  unsigned short* h_buf = (unsigned short*)(ws + 1573120);   // 16.8 MB
  unsigned short* xh    = (unsigned short*)(ws + 18350336);  // 4.2 MB
  unsigned* qk1         = (unsigned*)(ws + 22544640);        // 16.8 MB (nibbles along K, interleaved)
  unsigned* qk2         = (unsigned*)(ws + 39321856);        // 16.8 MB
  unsigned short* p_buf = (unsigned short*)(ws + 56099072);  // 33.6 MB
  float* partial        = (float*)(ws + 89653504);           // 4 MB (8-way k-split logits)

  hipMemsetAsync(counts, 0, 256, stream);

  cast_x_kernel<<<(T_TOK * HID / 4) / 256, 256, 0, stream>>>(x, xh);
  logits_f32_kernel<<<dim3(T_TOK / 64, HID / 128), 256, 0, stream>>>(x, gate_w, partial);
  topk_kernel<<<T_TOK / 4, 256, 0, stream>>>(partial, counts, tok_list, hslot_list, cw_list);
  repack_kernel<<<dim3(C1 / 512, HID / 16), 256, 0, stream>>>(qw1, qk1, HID, C1);
  repack_kernel<<<dim3(C2 / 512, IMED / 16), 256, 0, stream>>>(qw2, qk2, IMED, C2);

  mfma_gemm1<<<dim3(IMED / 64, T_TOK / 64, EXP), 256, 0, stream>>>(
      xh, qk1, qz1, sc1, counts, tok_list, hslot_list, cw_list, h_buf);
  mfma_gemm2<<<dim3(HID / 64, T_TOK / 64, EXP), 256, 0, stream>>>(
      h_buf, qk2, qz2, sc2, counts, hslot_list, p_buf);
  reduce_kernel<<<(T_TOK * HID / 8) / 256, 256, 0, stream>>>(p_buf, out);
}